// Round 14
// baseline (828.915 us; speedup 1.0000x reference)
//
#include <hip/hip_runtime.h>
#include <hip/hip_bf16.h>

#define NB 8
#define NV 200
#define NE 40000
#define NH 128
#define NL 3
#define EBLK 157        // edge kernels: ceil(NE/256), 256 edges/block (8 waves x 2x16)
#define NPART 32        // agg: edge-slices per graph; 8*32 = 256 blocks = 1/CU

typedef __attribute__((ext_vector_type(8))) __bf16 bf16x8;
typedef __attribute__((ext_vector_type(8))) short s16x8;
typedef __attribute__((ext_vector_type(4))) float f32x4;

__device__ inline float sigmoidf_(float x){ return 1.0f/(1.0f + __expf(-x)); }

__device__ inline short f2b(float f){
  union{ float f; unsigned u; } v; v.f = f;
  unsigned u = v.u;
  u += 0x7fffu + ((u >> 16) & 1u);
  return (short)(u >> 16);
}
__device__ inline float b2f(short s){
  union{ unsigned u; float f; } v; v.u = ((unsigned)(unsigned short)s) << 16;
  return v.f;
}
__device__ inline void splitb(float x, short &hi, short &lo){
  hi = f2b(x);
  lo = f2b(x - b2f(hi));
}

// ---------------- embed nodes ----------------
__global__ __launch_bounds__(256) void k_embed_nodes(
    const float* __restrict__ x, const float* __restrict__ nW,
    const float* __restrict__ nb, float* __restrict__ xh)
{
  int i = blockIdx.x*256 + threadIdx.x;
  if (i >= NB*NV*NH) return;
  int h  = i & (NH-1);
  int bv = i >> 7;
  xh[i] = x[bv*2+0]*nW[h] + x[bv*2+1]*nW[NH+h] + nb[h];
}

// ---------------- weight transpose to split bf16 ----------------
// Wt + m*NH*NH -> hi of matrix m; Wt + (4+m)*NH*NH -> lo.
// m = 0..2: A_W[l] linear:  Wt[n][c] = W[c][n]
// m = 3:    out_W1 sigma:   Wt[n][c] = W1[sigma(c)][n],
//           sigma(c) = 32*(c>>5) + 16*((c>>2)&1) + 4*((c>>3)&3) + (c&3)
__global__ __launch_bounds__(256) void k_trans_w(
    const float* __restrict__ AW, const float* __restrict__ oW1,
    short* __restrict__ Wt)
{
  int m = blockIdx.x;                         // 0..3
  const float* src = (m < 3) ? (AW + m*NH*NH) : oW1;
  short* dhi = Wt + (size_t)m*NH*NH;
  short* dlo = Wt + (size_t)(4+m)*NH*NH;
  for (int i = threadIdx.x; i < NH*NH; i += 256){
    int n = i >> 7, c = i & 127;
    int k;
    if (m < 3){
      k = c;
    } else {
      int kk = c >> 5, lg = (c >> 3) & 3, jh = (c >> 2) & 1, jl = c & 3;
      k = 32*kk + 16*jh + 4*lg + jl;
    }
    short hi, lo;
    splitb(src[k*NH + n], hi, lo);
    dhi[i] = hi; dlo[i] = lo;
  }
}

// ---------------- zero agg ----------------
__global__ __launch_bounds__(256) void k_zero_f(float* __restrict__ p, int n4){
  int i = blockIdx.x*256 + threadIdx.x;
  if (i < n4) *(f32x4*)(p + i*4) = (f32x4){0.f,0.f,0.f,0.f};
}

// ---------------- node: (optional xh update from prev layer) + 4 matmuls ----------------
__global__ __launch_bounds__(256) void k_node_mm(
    float* __restrict__ xh, const float* __restrict__ agg,
    const float* __restrict__ VWl, const float* __restrict__ Vbl,
    const float* __restrict__ BWl, const float* __restrict__ Bbl,
    const float* __restrict__ CWl, const float* __restrict__ Cbl,
    const float* __restrict__ UWl, const float* __restrict__ Ubl,
    float* __restrict__ vx, float* __restrict__ bx,
    float* __restrict__ cx, float* __restrict__ ux,
    int do_update)
{
  __shared__ float sx[NH];
  int b = blockIdx.x / NV, v = blockIdx.x % NV;
  size_t row = (size_t)b*NV + v;
  float* xr = xh + row*NH;
  int ht = threadIdx.x;
  if (ht < NH){
    float xv = xr[ht];
    if (do_update){
      float u = ux[row*NH + ht] + agg[row*NH + ht];
      xv += u > 0.f ? u : 0.f;
      xr[ht] = xv;
    }
    sx[ht] = xv;
  }
  __syncthreads();
  #pragma unroll
  for (int pass=0; pass<2; pass++){
    int t = threadIdx.x + pass*256;
    int mat = t >> 7, h = t & 127;
    const float* W = (mat==0) ? VWl : (mat==1) ? BWl : (mat==2) ? CWl : UWl;
    const float* bs = (mat==0) ? Vbl : (mat==1) ? Bbl : (mat==2) ? Cbl : Ubl;
    float* op = (mat==0) ? vx : (mat==1) ? bx : (mat==2) ? cx : ux;
    float acc = bs[h];
    #pragma unroll 8
    for (int k=0;k<NH;k++) acc += sx[k]*W[k*NH + h];
    op[row*NH + h] = acc;
  }
}

// ---------------- edge-parallel aggregation with LDS accumulation ----------------
// One block per (graph, edge-slice). s_agg[NV][NH] in LDS (102.4 KB); streamed
// coalesced eh reads (NO CSR); atomicAdd into LDS (h-consecutive -> conflict-free);
// one global atomicAdd flush per element. agg must be pre-zeroed.
__global__ __launch_bounds__(512) void k_agg2(
    const float* __restrict__ eh, const float* __restrict__ evec,
    const float* __restrict__ eWe, const float* __restrict__ ebe,
    const float* __restrict__ vx, const int* __restrict__ ei,
    float* __restrict__ agg, int is_l0)
{
  __shared__ float s_agg[NV*NH];        // 102400 B
  for (int i = threadIdx.x; i < NV*NH; i += 512) s_agg[i] = 0.f;
  __syncthreads();

  int part = blockIdx.x % NPART;
  int b    = blockIdx.x / NPART;
  int h    = threadIdx.x & 127;
  int sub  = threadIdx.x >> 7;          // 0..3
  const int* srcp = ei + b*2*NE;
  const int* dstp = srcp + NE;
  const float* ehg = eh + (size_t)b*NE*NH;
  const float* evg = evec + (size_t)b*NE;
  const float* vxg = vx + (size_t)b*NV*NH;
  float wh = eWe[h], bh = ebe[h];
  int e0 = part*(NE/NPART);             // 40000/32 = 1250
  int e1 = e0 + NE/NPART;

  int e = e0 + sub;
  for (; e + 12 < e1; e += 16){
    int sv[4], dv[4];
    float a[4], w[4];
    #pragma unroll
    for (int j=0;j<4;j++){ sv[j] = srcp[e + 4*j]; dv[j] = dstp[e + 4*j]; }
    if (is_l0){
      #pragma unroll
      for (int j=0;j<4;j++) a[j] = evg[e + 4*j]*wh + bh;
    } else {
      #pragma unroll
      for (int j=0;j<4;j++) a[j] = ehg[(size_t)(e + 4*j)*NH + h];
    }
    #pragma unroll
    for (int j=0;j<4;j++) w[j] = vxg[sv[j]*NH + h];
    #pragma unroll
    for (int j=0;j<4;j++) atomicAdd(&s_agg[dv[j]*NH + h], sigmoidf_(a[j])*w[j]);
  }
  for (; e < e1; e += 4){
    int sv = srcp[e], dv = dstp[e];
    float a = is_l0 ? (evg[e]*wh + bh) : ehg[(size_t)e*NH + h];
    atomicAdd(&s_agg[dv*NH + h], sigmoidf_(a)*vxg[sv*NH + h]);
  }

  __syncthreads();
  float* aggg = agg + (size_t)b*NV*NH;
  for (int i = threadIdx.x; i < NV*NH; i += 512){
    float v = s_agg[i];
    if (v != 0.f) atomicAdd(&aggg[i], v);
  }
}

// ---------------- edge update (layers 0,1) — round-9 proven form ----------------
// 512 threads (8 waves x 32 edges). W hi+lo in 64KB LDS (XOR swizzle). One tile per block.
__global__ __launch_bounds__(512) void k_edge_update(
    float* __restrict__ eh, const short* __restrict__ Wt,
    const float* __restrict__ Ab, const float* __restrict__ bx,
    const float* __restrict__ cx, const int* __restrict__ ei,
    const float* __restrict__ evec, const float* __restrict__ eWe,
    const float* __restrict__ ebe, int is_l0)
{
  __shared__ short sW[2*NH*NH];         // 64 KB: [0..16383]=hi, [16384..]=lo
  const short* Whi = Wt;
  const short* Wlo = Wt + 4*NH*NH;
  {
    #pragma unroll
    for (int i=0;i<8;i++){
      int sidx = (threadIdx.x + i*512)*8;       // short index 0..32767
      int p = sidx >> 14, r = sidx & 16383;
      int hh = r >> 7, kw = r & 127;
      const short* src = p ? Wlo : Whi;
      s16x8 vv = *(const s16x8*)(src + r);
      *(s16x8*)(sW + p*16384 + hh*128 + (kw ^ ((hh&7)<<3))) = vv;
    }
  }
  __syncthreads();

  int blk  = blockIdx.x % EBLK;
  int b    = blockIdx.x / EBLK;
  int wave = threadIdx.x >> 6;
  int lane = threadIdx.x & 63;
  int l15 = lane & 15, lg = lane >> 4;
  int eA = blk*256 + wave*32 + l15;
  int eB = eA + 16;
  int eAc = eA < NE ? eA : NE-1;
  int eBc = eB < NE ? eB : NE-1;
  float* ehg = eh + (size_t)b*NE*NH;
  const int* srcp = ei + b*2*NE;
  int svA = srcp[eAc], dvA = srcp[NE+eAc];
  int svB = srcp[eBc], dvB = srcp[NE+eBc];

  float evA = 0.f, evB = 0.f;
  f32x4 rA[8], rB[8];
  if (is_l0){
    evA = evec[(size_t)b*NE + eAc];
    evB = evec[(size_t)b*NE + eBc];
    #pragma unroll
    for (int kk=0;kk<4;kk++){
      f32x4 w0 = *(const f32x4*)(eWe + kk*32 + lg*8);
      f32x4 w1 = *(const f32x4*)(eWe + kk*32 + lg*8 + 4);
      f32x4 q0 = *(const f32x4*)(ebe + kk*32 + lg*8);
      f32x4 q1 = *(const f32x4*)(ebe + kk*32 + lg*8 + 4);
      #pragma unroll
      for (int j=0;j<4;j++){
        rA[2*kk][j]   = evA*w0[j] + q0[j];
        rA[2*kk+1][j] = evA*w1[j] + q1[j];
        rB[2*kk][j]   = evB*w0[j] + q0[j];
        rB[2*kk+1][j] = evB*w1[j] + q1[j];
      }
    }
  } else {
    const float* pA = ehg + (size_t)eAc*NH + lg*8;
    const float* pB = ehg + (size_t)eBc*NH + lg*8;
    #pragma unroll
    for (int kk=0;kk<4;kk++){
      rA[2*kk]   = *(const f32x4*)(pA + kk*32);
      rA[2*kk+1] = *(const f32x4*)(pA + kk*32 + 4);
    }
    #pragma unroll
    for (int kk=0;kk<4;kk++){
      rB[2*kk]   = *(const f32x4*)(pB + kk*32);
      rB[2*kk+1] = *(const f32x4*)(pB + kk*32 + 4);
    }
  }

  bf16x8 ahA[4], alA[4], ahB[4], alB[4];
  #pragma unroll
  for (int kk=0;kk<4;kk++){
    union{ short s[8]; bf16x8 v; } uh, ul;
    #pragma unroll
    for (int j=0;j<4;j++){
      splitb(rA[2*kk][j],   uh.s[j],   ul.s[j]);
      splitb(rA[2*kk+1][j], uh.s[4+j], ul.s[4+j]);
    }
    ahA[kk] = uh.v; alA[kk] = ul.v;
  }
  #pragma unroll
  for (int kk=0;kk<4;kk++){
    union{ short s[8]; bf16x8 v; } uh, ul;
    #pragma unroll
    for (int j=0;j<4;j++){
      splitb(rB[2*kk][j],   uh.s[j],   ul.s[j]);
      splitb(rB[2*kk+1][j], uh.s[4+j], ul.s[4+j]);
    }
    ahB[kk] = uh.v; alB[kk] = ul.v;
  }

  f32x4 accA[8], accB[8];
  #pragma unroll
  for (int n=0;n<8;n++){ accA[n] = (f32x4){0.f,0.f,0.f,0.f}; accB[n] = (f32x4){0.f,0.f,0.f,0.f}; }

  #pragma unroll
  for (int kk=0;kk<4;kk++){
    #pragma unroll
    for (int n=0;n<8;n++){
      int row = n*16 + l15;
      int cofs = (kk*32 + lg*8) ^ ((l15&7)<<3);
      union{ s16x8 s; bf16x8 v; } wh, wl;
      wh.s = *(const s16x8*)(sW + row*128 + cofs);
      wl.s = *(const s16x8*)(sW + 16384 + row*128 + cofs);
      accA[n] = __builtin_amdgcn_mfma_f32_16x16x32_bf16(wh.v, ahA[kk], accA[n], 0, 0, 0);
      accA[n] = __builtin_amdgcn_mfma_f32_16x16x32_bf16(wh.v, alA[kk], accA[n], 0, 0, 0);
      accA[n] = __builtin_amdgcn_mfma_f32_16x16x32_bf16(wl.v, ahA[kk], accA[n], 0, 0, 0);
      accB[n] = __builtin_amdgcn_mfma_f32_16x16x32_bf16(wh.v, ahB[kk], accB[n], 0, 0, 0);
      accB[n] = __builtin_amdgcn_mfma_f32_16x16x32_bf16(wh.v, alB[kk], accB[n], 0, 0, 0);
      accB[n] = __builtin_amdgcn_mfma_f32_16x16x32_bf16(wl.v, ahB[kk], accB[n], 0, 0, 0);
    }
  }

  const float* bxA = bx + ((size_t)b*NV + svA)*NH;
  const float* cxA = cx + ((size_t)b*NV + dvA)*NH;
  const float* bxB = bx + ((size_t)b*NV + svB)*NH;
  const float* cxB = cx + ((size_t)b*NV + dvB)*NH;
  float* ehA = ehg + (size_t)eAc*NH;
  float* ehB = ehg + (size_t)eBc*NH;
  #pragma unroll
  for (int n=0;n<8;n++){
    int h0 = n*16 + lg*4;
    f32x4 ab4 = *(const f32x4*)(Ab + h0);
    f32x4 bA = *(const f32x4*)(bxA + h0);
    f32x4 cA = *(const f32x4*)(cxA + h0);
    f32x4 bB = *(const f32x4*)(bxB + h0);
    f32x4 cB = *(const f32x4*)(cxB + h0);
    f32x4 oA, oB;
    if (is_l0){
      f32x4 w4 = *(const f32x4*)(eWe + h0);
      f32x4 q4 = *(const f32x4*)(ebe + h0);
      #pragma unroll
      for (int j=0;j<4;j++){ oA[j] = evA*w4[j] + q4[j]; oB[j] = evB*w4[j] + q4[j]; }
    } else {
      oA = *(const f32x4*)(ehA + h0);
      oB = *(const f32x4*)(ehB + h0);
    }
    f32x4 nA, nB;
    #pragma unroll
    for (int j=0;j<4;j++){
      float vA = accA[n][j] + ab4[j] + bA[j] + cA[j];
      vA = vA > 0.f ? vA : 0.f;
      nA[j] = oA[j] + vA;
      float vB = accB[n][j] + ab4[j] + bB[j] + cB[j];
      vB = vB > 0.f ? vB : 0.f;
      nB[j] = oB[j] + vB;
    }
    if (eA < NE) *(f32x4*)(ehA + h0) = nA;
    if (eB < NE) *(f32x4*)(ehB + h0) = nB;
  }
}

// ---------------- fused layer-2 edge update + output MLP — round-9 proven form ------
// 512 threads, 128 KB LDS (all four matrices), one barrier.
__global__ __launch_bounds__(512) void k_edge_out(
    const float* __restrict__ eh, const short* __restrict__ Wt,
    const float* __restrict__ Ab, const float* __restrict__ bx,
    const float* __restrict__ cx, const int* __restrict__ ei,
    const float* __restrict__ b1, const float* __restrict__ W2,
    const float* __restrict__ b2, float* __restrict__ out)
{
  __shared__ short sW[4*NH*NH];         // 128 KB: p0=A2hi p1=A2lo p2=W1hi p3=W1lo
  {
    const short* A2hi = Wt + 2*NH*NH;
    const short* A2lo = Wt + 6*NH*NH;
    const short* W1hi = Wt + 3*NH*NH;
    const short* W1lo = Wt + 7*NH*NH;
    #pragma unroll
    for (int i=0;i<16;i++){
      int sidx = (threadIdx.x + i*512)*8;
      int p = i >> 2;
      int r = sidx & 16383;
      int hh = r >> 7, kw = r & 127;
      const short* src = (p==0)? A2hi : (p==1)? A2lo : (p==2)? W1hi : W1lo;
      s16x8 vv = *(const s16x8*)(src + r);
      *(s16x8*)(sW + p*16384 + hh*128 + (kw ^ ((hh&7)<<3))) = vv;
    }
  }
  __syncthreads();   // the ONLY barrier

  int blk  = blockIdx.x % EBLK;
  int b    = blockIdx.x / EBLK;
  int wave = threadIdx.x >> 6;
  int lane = threadIdx.x & 63;
  int l15 = lane & 15, lg = lane >> 4;
  int eA = blk*256 + wave*32 + l15;
  int eB = eA + 16;
  int eAc = eA < NE ? eA : NE-1;
  int eBc = eB < NE ? eB : NE-1;
  const float* ehg = eh + (size_t)b*NE*NH;
  const int* srcp = ei + b*2*NE;
  int svA = srcp[eAc], dvA = srcp[NE+eAc];
  int svB = srcp[eBc], dvB = srcp[NE+eBc];

  const float* pA = ehg + (size_t)eAc*NH + lg*8;
  const float* pB = ehg + (size_t)eBc*NH + lg*8;
  f32x4 rA[8], rB[8];
  #pragma unroll
  for (int kk=0;kk<4;kk++){
    rA[2*kk]   = *(const f32x4*)(pA + kk*32);
    rA[2*kk+1] = *(const f32x4*)(pA + kk*32 + 4);
  }
  #pragma unroll
  for (int kk=0;kk<4;kk++){
    rB[2*kk]   = *(const f32x4*)(pB + kk*32);
    rB[2*kk+1] = *(const f32x4*)(pB + kk*32 + 4);
  }

  bf16x8 ahA[4], alA[4], ahB[4], alB[4];
  #pragma unroll
  for (int kk=0;kk<4;kk++){
    union{ short s[8]; bf16x8 v; } uh, ul;
    #pragma unroll
    for (int j=0;j<4;j++){
      splitb(rA[2*kk][j],   uh.s[j],   ul.s[j]);
      splitb(rA[2*kk+1][j], uh.s[4+j], ul.s[4+j]);
    }
    ahA[kk] = uh.v; alA[kk] = ul.v;
  }
  #pragma unroll
  for (int kk=0;kk<4;kk++){
    union{ short s[8]; bf16x8 v; } uh, ul;
    #pragma unroll
    for (int j=0;j<4;j++){
      splitb(rB[2*kk][j],   uh.s[j],   ul.s[j]);
      splitb(rB[2*kk+1][j], uh.s[4+j], ul.s[4+j]);
    }
    ahB[kk] = uh.v; alB[kk] = ul.v;
  }

  f32x4 accA[8], accB[8];
  #pragma unroll
  for (int n=0;n<8;n++){ accA[n] = (f32x4){0.f,0.f,0.f,0.f}; accB[n] = (f32x4){0.f,0.f,0.f,0.f}; }
  #pragma unroll
  for (int kk=0;kk<4;kk++){
    #pragma unroll
    for (int n=0;n<8;n++){
      int row = n*16 + l15;
      int cofs = (kk*32 + lg*8) ^ ((l15&7)<<3);
      union{ s16x8 s; bf16x8 v; } wh, wl;
      wh.s = *(const s16x8*)(sW + row*128 + cofs);
      wl.s = *(const s16x8*)(sW + 16384 + row*128 + cofs);
      accA[n] = __builtin_amdgcn_mfma_f32_16x16x32_bf16(wh.v, ahA[kk], accA[n], 0, 0, 0);
      accA[n] = __builtin_amdgcn_mfma_f32_16x16x32_bf16(wh.v, alA[kk], accA[n], 0, 0, 0);
      accA[n] = __builtin_amdgcn_mfma_f32_16x16x32_bf16(wl.v, ahA[kk], accA[n], 0, 0, 0);
      accB[n] = __builtin_amdgcn_mfma_f32_16x16x32_bf16(wh.v, ahB[kk], accB[n], 0, 0, 0);
      accB[n] = __builtin_amdgcn_mfma_f32_16x16x32_bf16(wh.v, alB[kk], accB[n], 0, 0, 0);
      accB[n] = __builtin_amdgcn_mfma_f32_16x16x32_bf16(wl.v, ahB[kk], accB[n], 0, 0, 0);
    }
  }

  // epilogue: compute eh3 per (kk, half) and convert DIRECTLY to split-bf16
  // B-fragments (k-slot (kk,lg,j): h = 32kk+16(j>>2)+4lg+(j&3)); no f32 array.
  const float* bxA = bx + ((size_t)b*NV + svA)*NH;
  const float* cxA = cx + ((size_t)b*NV + dvA)*NH;
  const float* bxB = bx + ((size_t)b*NV + svB)*NH;
  const float* cxB = cx + ((size_t)b*NV + dvB)*NH;
  const float* ehA = ehg + (size_t)eAc*NH;
  const float* ehB = ehg + (size_t)eBc*NH;
  bf16x8 qhA[4], qlA[4], qhB[4], qlB[4];
  #pragma unroll
  for (int kk=0;kk<4;kk++){
    union{ short s[8]; bf16x8 v; } uhA, ulA, uhB, ulB;
    #pragma unroll
    for (int half=0; half<2; half++){
      int n = 2*kk + half;
      int h0 = n*16 + lg*4;
      f32x4 ab4 = *(const f32x4*)(Ab + h0);
      f32x4 bA4 = *(const f32x4*)(bxA + h0);
      f32x4 cA4 = *(const f32x4*)(cxA + h0);
      f32x4 oA4 = *(const f32x4*)(ehA + h0);
      f32x4 bB4 = *(const f32x4*)(bxB + h0);
      f32x4 cB4 = *(const f32x4*)(cxB + h0);
      f32x4 oB4 = *(const f32x4*)(ehB + h0);
      #pragma unroll
      for (int j=0;j<4;j++){
        float vA = accA[n][j] + ab4[j] + bA4[j] + cA4[j];
        vA = vA > 0.f ? vA : 0.f;
        float e3A = oA4[j] + vA;
        splitb(e3A, uhA.s[half*4+j], ulA.s[half*4+j]);
        float vB = accB[n][j] + ab4[j] + bB4[j] + cB4[j];
        vB = vB > 0.f ? vB : 0.f;
        float e3B = oB4[j] + vB;
        splitb(e3B, uhB.s[half*4+j], ulB.s[half*4+j]);
      }
    }
    qhA[kk] = uhA.v; qlA[kk] = ulA.v;
    qhB[kk] = uhB.v; qlB[kk] = ulB.v;
  }

  // Phase 2: W1 matmul, all operands LDS-resident (p2=hi, p3=lo)
  f32x4 acc2A[8], acc2B[8];
  #pragma unroll
  for (int n=0;n<8;n++){ acc2A[n] = (f32x4){0.f,0.f,0.f,0.f}; acc2B[n] = (f32x4){0.f,0.f,0.f,0.f}; }
  #pragma unroll
  for (int kk=0;kk<4;kk++){
    #pragma unroll
    for (int n=0;n<8;n++){
      int row = n*16 + l15;
      int cofs = (kk*32 + lg*8) ^ ((l15&7)<<3);
      union{ s16x8 s; bf16x8 v; } wh, wl;
      wh.s = *(const s16x8*)(sW + 2*16384 + row*128 + cofs);
      wl.s = *(const s16x8*)(sW + 3*16384 + row*128 + cofs);
      acc2A[n] = __builtin_amdgcn_mfma_f32_16x16x32_bf16(wh.v, qhA[kk], acc2A[n], 0, 0, 0);
      acc2A[n] = __builtin_amdgcn_mfma_f32_16x16x32_bf16(wh.v, qlA[kk], acc2A[n], 0, 0, 0);
      acc2A[n] = __builtin_amdgcn_mfma_f32_16x16x32_bf16(wl.v, qhA[kk], acc2A[n], 0, 0, 0);
      acc2B[n] = __builtin_amdgcn_mfma_f32_16x16x32_bf16(wh.v, qhB[kk], acc2B[n], 0, 0, 0);
      acc2B[n] = __builtin_amdgcn_mfma_f32_16x16x32_bf16(wh.v, qlB[kk], acc2B[n], 0, 0, 0);
      acc2B[n] = __builtin_amdgcn_mfma_f32_16x16x32_bf16(wl.v, qhB[kk], acc2B[n], 0, 0, 0);
    }
  }

  // W2 reduction + sigmoid
  float p0A = 0.f, p1A = 0.f, p0B = 0.f, p1B = 0.f;
  #pragma unroll
  for (int n=0;n<8;n++){
    int h0 = n*16 + lg*4;
    f32x4 b14 = *(const f32x4*)(b1 + h0);
    f32x4 wA  = *(const f32x4*)(W2 + h0*2);
    f32x4 wB  = *(const f32x4*)(W2 + h0*2 + 4);
    #pragma unroll
    for (int j=0;j<4;j++){
      float w20 = (j<2) ? wA[2*j]   : wB[2*(j-2)];
      float w21 = (j<2) ? wA[2*j+1] : wB[2*(j-2)+1];
      float hA = acc2A[n][j] + b14[j]; hA = hA > 0.f ? hA : 0.f;
      float hB = acc2B[n][j] + b14[j]; hB = hB > 0.f ? hB : 0.f;
      p0A += hA*w20; p1A += hA*w21;
      p0B += hB*w20; p1B += hB*w21;
    }
  }
  p0A += __shfl_xor(p0A, 16, 64); p0A += __shfl_xor(p0A, 32, 64);
  p1A += __shfl_xor(p1A, 16, 64); p1A += __shfl_xor(p1A, 32, 64);
  p0B += __shfl_xor(p0B, 16, 64); p0B += __shfl_xor(p0B, 32, 64);
  p1B += __shfl_xor(p1B, 16, 64); p1B += __shfl_xor(p1B, 32, 64);
  if (lg == 0){
    float bb0 = b2[0], bb1 = b2[1];
    if (eA < NE){
      float2 r; r.x = sigmoidf_(p0A + bb0); r.y = sigmoidf_(p1A + bb1);
      *(float2*)(out + ((size_t)b*NE + eA)*2) = r;
    }
    if (eB < NE){
      float2 r; r.x = sigmoidf_(p0B + bb0); r.y = sigmoidf_(p1B + bb1);
      *(float2*)(out + ((size_t)b*NE + eB)*2) = r;
    }
  }
}

extern "C" void kernel_launch(void* const* d_in, const int* in_sizes, int n_in,
                              void* d_out, int out_size, void* d_ws, size_t ws_size,
                              hipStream_t stream)
{
  const float* x   = (const float*)d_in[0];
  const float* e   = (const float*)d_in[1];
  const int*   ei  = (const int*)d_in[2];
  const float* nW  = (const float*)d_in[3];
  const float* nb  = (const float*)d_in[4];
  const float* eW  = (const float*)d_in[5];
  const float* eb  = (const float*)d_in[6];
  const float* UW  = (const float*)d_in[7];
  const float* Ub  = (const float*)d_in[8];
  const float* VW  = (const float*)d_in[9];
  const float* Vb  = (const float*)d_in[10];
  const float* AW  = (const float*)d_in[11];
  const float* Ab  = (const float*)d_in[12];
  const float* BW  = (const float*)d_in[13];
  const float* Bb  = (const float*)d_in[14];
  const float* CW  = (const float*)d_in[15];
  const float* Cb  = (const float*)d_in[16];
  const float* oW1 = (const float*)d_in[17];
  const float* ob1 = (const float*)d_in[18];
  const float* oW2 = (const float*)d_in[19];
  const float* ob2 = (const float*)d_in[20];
  float* out = (float*)d_out;

  char* ws = (char*)d_ws;
  size_t off = 0;
  auto alloc = [&](size_t bytes)->char*{
    char* p = ws + off;
    off += (bytes + 255) & ~(size_t)255;
    return p;
  };
  float* eh     = (float*)alloc((size_t)NB*NE*NH*4);
  float* xh     = (float*)alloc((size_t)NB*NV*NH*4);
  float* vx     = (float*)alloc((size_t)NB*NV*NH*4);
  float* bx     = (float*)alloc((size_t)NB*NV*NH*4);
  float* cx     = (float*)alloc((size_t)NB*NV*NH*4);
  float* ux     = (float*)alloc((size_t)NB*NV*NH*4);
  float* agg    = (float*)alloc((size_t)NB*NV*NH*4);
  short* Wt     = (short*)alloc((size_t)8*NH*NH*2);
  (void)ws_size; (void)in_sizes; (void)n_in; (void)out_size;

  k_embed_nodes<<<(NB*NV*NH+255)/256, 256, 0, stream>>>(x, nW, nb, xh);
  k_trans_w<<<4, 256, 0, stream>>>(AW, oW1, Wt);

  for (int l=0; l<NL; l++){
    k_node_mm<<<NB*NV, 256, 0, stream>>>(xh, agg,
        VW + l*NH*NH, Vb + l*NH, BW + l*NH*NH, Bb + l*NH,
        CW + l*NH*NH, Cb + l*NH, UW + l*NH*NH, Ub + l*NH,
        vx, bx, cx, ux, l > 0 ? 1 : 0);
    if (l < NL-1){  // layer-2 agg only feeds dead xh_3
      k_zero_f<<<(NB*NV*NH/4+255)/256, 256, 0, stream>>>(agg, NB*NV*NH/4);
      k_agg2<<<NB*NPART, 512, 0, stream>>>(eh, e, eW, eb, vx, ei, agg, l==0 ? 1 : 0);
    }
    if (l < NL-1)
      k_edge_update<<<NB*EBLK, 512, 0, stream>>>(eh, Wt + l*NH*NH, Ab + l*NH, bx, cx, ei,
                                                 e, eW, eb, l==0 ? 1 : 0);
    else
      k_edge_out<<<NB*EBLK, 512, 0, stream>>>(eh, Wt, Ab + l*NH, bx, cx, ei,
                                              ob1, oW2, ob2, out);
  }
}

// Round 15
// 531.268 us; speedup vs baseline: 1.5603x; 1.5603x over previous
//
#include <hip/hip_runtime.h>
#include <hip/hip_bf16.h>

#define NB 8
#define NV 200
#define NE 40000
#define NH 128
#define NL 3
#define EBLK 157        // ceil(NE/256): 256 edges per block (8 waves x 2 sub-tiles of 16)

typedef __attribute__((ext_vector_type(8))) __bf16 bf16x8;
typedef __attribute__((ext_vector_type(8))) short s16x8;
typedef __attribute__((ext_vector_type(4))) float f32x4;

__device__ inline float sigmoidf_(float x){ return 1.0f/(1.0f + __expf(-x)); }

__device__ inline short f2b(float f){
  union{ float f; unsigned u; } v; v.f = f;
  unsigned u = v.u;
  u += 0x7fffu + ((u >> 16) & 1u);
  return (short)(u >> 16);
}
__device__ inline float b2f(short s){
  union{ unsigned u; float f; } v; v.u = ((unsigned)(unsigned short)s) << 16;
  return v.f;
}
__device__ inline void splitb(float x, short &hi, short &lo){
  hi = f2b(x);
  lo = f2b(x - b2f(hi));
}

// ---------------- embed nodes ----------------
__global__ __launch_bounds__(256) void k_embed_nodes(
    const float* __restrict__ x, const float* __restrict__ nW,
    const float* __restrict__ nb, float* __restrict__ xh)
{
  int i = blockIdx.x*256 + threadIdx.x;
  if (i >= NB*NV*NH) return;
  int h  = i & (NH-1);
  int bv = i >> 7;
  xh[i] = x[bv*2+0]*nW[h] + x[bv*2+1]*nW[NH+h] + nb[h];
}

// ---------------- weight transpose to split bf16 ----------------
// Wt + m*NH*NH -> hi of matrix m; Wt + (4+m)*NH*NH -> lo.
// m = 0..2: A_W[l] linear:  Wt[n][c] = W[c][n]
// m = 3:    out_W1 sigma:   Wt[n][c] = W1[sigma(c)][n],
//           sigma(c) = 32*(c>>5) + 16*((c>>2)&1) + 4*((c>>3)&3) + (c&3)
__global__ __launch_bounds__(256) void k_trans_w(
    const float* __restrict__ AW, const float* __restrict__ oW1,
    short* __restrict__ Wt)
{
  int m = blockIdx.x;                         // 0..3
  const float* src = (m < 3) ? (AW + m*NH*NH) : oW1;
  short* dhi = Wt + (size_t)m*NH*NH;
  short* dlo = Wt + (size_t)(4+m)*NH*NH;
  for (int i = threadIdx.x; i < NH*NH; i += 256){
    int n = i >> 7, c = i & 127;
    int k;
    if (m < 3){
      k = c;
    } else {
      int kk = c >> 5, lg = (c >> 3) & 3, jh = (c >> 2) & 1, jl = c & 3;
      k = 32*kk + 16*jh + 4*lg + jl;
    }
    short hi, lo;
    splitb(src[k*NH + n], hi, lo);
    dhi[i] = hi; dlo[i] = lo;
  }
}

// ---------------- CSR build ----------------
__global__ __launch_bounds__(256) void k_zero(int* __restrict__ p, int n){
  int i = blockIdx.x*256 + threadIdx.x;
  if (i < n) p[i] = 0;
}

__global__ __launch_bounds__(256) void k_count(const int* __restrict__ ei, int* __restrict__ counts){
  int i = blockIdx.x*256 + threadIdx.x;
  if (i >= NB*NE) return;
  int b = i / NE, e = i % NE;
  int dv = ei[b*2*NE + NE + e];
  atomicAdd(&counts[b*NV + dv], 1);
}

__global__ void k_scan(const int* __restrict__ counts, int* __restrict__ offs, int* __restrict__ cursor){
  int b = blockIdx.x;
  if (threadIdx.x == 0){
    int run = 0;
    for (int v=0; v<NV; v++){
      offs[b*(NV+1)+v] = run;
      cursor[b*NV+v]   = run;
      run += counts[b*NV+v];
    }
    offs[b*(NV+1)+NV] = run;
  }
}

__global__ __launch_bounds__(256) void k_scatter(const int* __restrict__ ei, int* __restrict__ cursor, int* __restrict__ csr){
  int i = blockIdx.x*256 + threadIdx.x;
  if (i >= NB*NE) return;
  int b = i / NE, e = i % NE;
  int dv = ei[b*2*NE + NE + e];
  int pos = atomicAdd(&cursor[b*NV + dv], 1);
  csr[(size_t)b*NE + pos] = e;
}

// ---------------- node: (optional xh update from prev layer) + 4 matmuls ----------------
__global__ __launch_bounds__(256) void k_node_mm(
    float* __restrict__ xh, const float* __restrict__ agg,
    const float* __restrict__ VWl, const float* __restrict__ Vbl,
    const float* __restrict__ BWl, const float* __restrict__ Bbl,
    const float* __restrict__ CWl, const float* __restrict__ Cbl,
    const float* __restrict__ UWl, const float* __restrict__ Ubl,
    float* __restrict__ vx, float* __restrict__ bx,
    float* __restrict__ cx, float* __restrict__ ux,
    int do_update)
{
  __shared__ float sx[NH];
  int b = blockIdx.x / NV, v = blockIdx.x % NV;
  size_t row = (size_t)b*NV + v;
  float* xr = xh + row*NH;
  int ht = threadIdx.x;
  if (ht < NH){
    float xv = xr[ht];
    if (do_update){
      float u = ux[row*NH + ht];
      #pragma unroll
      for (int p=0;p<4;p++) u += agg[(size_t)p*NB*NV*NH + row*NH + ht];
      xv += u > 0.f ? u : 0.f;
      xr[ht] = xv;
    }
    sx[ht] = xv;
  }
  __syncthreads();
  #pragma unroll
  for (int pass=0; pass<2; pass++){
    int t = threadIdx.x + pass*256;
    int mat = t >> 7, h = t & 127;
    const float* W = (mat==0) ? VWl : (mat==1) ? BWl : (mat==2) ? CWl : UWl;
    const float* bs = (mat==0) ? Vbl : (mat==1) ? Bbl : (mat==2) ? Cbl : Ubl;
    float* op = (mat==0) ? vx : (mat==1) ? bx : (mat==2) ? cx : ux;
    float acc = bs[h];
    #pragma unroll 8
    for (int k=0;k<NH;k++) acc += sx[k]*W[k*NH + h];
    op[row*NH + h] = acc;
  }
}

// ---------------- aggregation (4 partial blocks per node) ----------------
__global__ __launch_bounds__(128) void k_agg(
    const float* __restrict__ eh, const float* __restrict__ evec,
    const float* __restrict__ eWe, const float* __restrict__ ebe,
    const float* __restrict__ vx, const int* __restrict__ ei,
    const int* __restrict__ csr, const int* __restrict__ offs,
    float* __restrict__ agg, int is_l0)
{
  int part = blockIdx.x & 3;
  int bv   = blockIdx.x >> 2;
  int b = bv / NV, v = bv % NV;
  int h = threadIdx.x;
  const int* srcp  = ei + b*2*NE;
  const int* csrg  = csr + (size_t)b*NE;
  const float* ehg = eh + (size_t)b*NE*NH;
  const float* evg = evec + (size_t)b*NE;
  const float* vxg = vx + (size_t)b*NV*NH;
  float wh = eWe[h], bh = ebe[h];
  int beg = offs[b*(NV+1)+v], end = offs[b*(NV+1)+v+1];
  int len = end - beg;
  int i    = beg + ((len*part) >> 2);
  int stop = beg + ((len*(part+1)) >> 2);
  float acc = 0.f;
  for (; i+8 <= stop; i += 8){
    int   eb[8], sb[8];
    float a[8], w[8];
    #pragma unroll
    for (int j=0;j<8;j++) eb[j] = csrg[i+j];
    #pragma unroll
    for (int j=0;j<8;j++) sb[j] = srcp[eb[j]];
    if (is_l0){
      #pragma unroll
      for (int j=0;j<8;j++) a[j] = evg[eb[j]]*wh + bh;
    } else {
      #pragma unroll
      for (int j=0;j<8;j++) a[j] = ehg[(size_t)eb[j]*NH + h];
    }
    #pragma unroll
    for (int j=0;j<8;j++) w[j] = vxg[sb[j]*NH + h];
    #pragma unroll
    for (int j=0;j<8;j++) acc += sigmoidf_(a[j]) * w[j];
  }
  for (; i < stop; i++){
    int e0 = csrg[i]; int s0 = srcp[e0];
    float a = is_l0 ? (evg[e0]*wh + bh) : ehg[(size_t)e0*NH+h];
    acc += sigmoidf_(a) * vxg[s0*NH+h];
  }
  agg[((size_t)part*NB*NV + (size_t)b*NV + v)*NH + h] = acc;
}

// ---------------- edge update (layers 0,1) — round-9 proven form ----------------
// 512 threads (8 waves x 32 edges). W hi+lo in 64KB LDS (XOR swizzle). One tile per block.
__global__ __launch_bounds__(512) void k_edge_update(
    float* __restrict__ eh, const short* __restrict__ Wt,
    const float* __restrict__ Ab, const float* __restrict__ bx,
    const float* __restrict__ cx, const int* __restrict__ ei,
    const float* __restrict__ evec, const float* __restrict__ eWe,
    const float* __restrict__ ebe, int is_l0)
{
  __shared__ short sW[2*NH*NH];         // 64 KB: [0..16383]=hi, [16384..]=lo
  const short* Whi = Wt;
  const short* Wlo = Wt + 4*NH*NH;
  {
    #pragma unroll
    for (int i=0;i<8;i++){
      int sidx = (threadIdx.x + i*512)*8;       // short index 0..32767
      int p = sidx >> 14, r = sidx & 16383;
      int hh = r >> 7, kw = r & 127;
      const short* src = p ? Wlo : Whi;
      s16x8 vv = *(const s16x8*)(src + r);
      *(s16x8*)(sW + p*16384 + hh*128 + (kw ^ ((hh&7)<<3))) = vv;
    }
  }
  __syncthreads();

  int blk  = blockIdx.x % EBLK;
  int b    = blockIdx.x / EBLK;
  int wave = threadIdx.x >> 6;
  int lane = threadIdx.x & 63;
  int l15 = lane & 15, lg = lane >> 4;
  int eA = blk*256 + wave*32 + l15;
  int eB = eA + 16;
  int eAc = eA < NE ? eA : NE-1;
  int eBc = eB < NE ? eB : NE-1;
  float* ehg = eh + (size_t)b*NE*NH;
  const int* srcp = ei + b*2*NE;
  int svA = srcp[eAc], dvA = srcp[NE+eAc];
  int svB = srcp[eBc], dvB = srcp[NE+eBc];

  float evA = 0.f, evB = 0.f;
  f32x4 rA[8], rB[8];
  if (is_l0){
    evA = evec[(size_t)b*NE + eAc];
    evB = evec[(size_t)b*NE + eBc];
    #pragma unroll
    for (int kk=0;kk<4;kk++){
      f32x4 w0 = *(const f32x4*)(eWe + kk*32 + lg*8);
      f32x4 w1 = *(const f32x4*)(eWe + kk*32 + lg*8 + 4);
      f32x4 q0 = *(const f32x4*)(ebe + kk*32 + lg*8);
      f32x4 q1 = *(const f32x4*)(ebe + kk*32 + lg*8 + 4);
      #pragma unroll
      for (int j=0;j<4;j++){
        rA[2*kk][j]   = evA*w0[j] + q0[j];
        rA[2*kk+1][j] = evA*w1[j] + q1[j];
        rB[2*kk][j]   = evB*w0[j] + q0[j];
        rB[2*kk+1][j] = evB*w1[j] + q1[j];
      }
    }
  } else {
    const float* pA = ehg + (size_t)eAc*NH + lg*8;
    const float* pB = ehg + (size_t)eBc*NH + lg*8;
    #pragma unroll
    for (int kk=0;kk<4;kk++){
      rA[2*kk]   = *(const f32x4*)(pA + kk*32);
      rA[2*kk+1] = *(const f32x4*)(pA + kk*32 + 4);
    }
    #pragma unroll
    for (int kk=0;kk<4;kk++){
      rB[2*kk]   = *(const f32x4*)(pB + kk*32);
      rB[2*kk+1] = *(const f32x4*)(pB + kk*32 + 4);
    }
  }

  bf16x8 ahA[4], alA[4], ahB[4], alB[4];
  #pragma unroll
  for (int kk=0;kk<4;kk++){
    union{ short s[8]; bf16x8 v; } uh, ul;
    #pragma unroll
    for (int j=0;j<4;j++){
      splitb(rA[2*kk][j],   uh.s[j],   ul.s[j]);
      splitb(rA[2*kk+1][j], uh.s[4+j], ul.s[4+j]);
    }
    ahA[kk] = uh.v; alA[kk] = ul.v;
  }
  #pragma unroll
  for (int kk=0;kk<4;kk++){
    union{ short s[8]; bf16x8 v; } uh, ul;
    #pragma unroll
    for (int j=0;j<4;j++){
      splitb(rB[2*kk][j],   uh.s[j],   ul.s[j]);
      splitb(rB[2*kk+1][j], uh.s[4+j], ul.s[4+j]);
    }
    ahB[kk] = uh.v; alB[kk] = ul.v;
  }

  f32x4 accA[8], accB[8];
  #pragma unroll
  for (int n=0;n<8;n++){ accA[n] = (f32x4){0.f,0.f,0.f,0.f}; accB[n] = (f32x4){0.f,0.f,0.f,0.f}; }

  #pragma unroll
  for (int kk=0;kk<4;kk++){
    #pragma unroll
    for (int n=0;n<8;n++){
      int row = n*16 + l15;
      int cofs = (kk*32 + lg*8) ^ ((l15&7)<<3);
      union{ s16x8 s; bf16x8 v; } wh, wl;
      wh.s = *(const s16x8*)(sW + row*128 + cofs);
      wl.s = *(const s16x8*)(sW + 16384 + row*128 + cofs);
      accA[n] = __builtin_amdgcn_mfma_f32_16x16x32_bf16(wh.v, ahA[kk], accA[n], 0, 0, 0);
      accA[n] = __builtin_amdgcn_mfma_f32_16x16x32_bf16(wh.v, alA[kk], accA[n], 0, 0, 0);
      accA[n] = __builtin_amdgcn_mfma_f32_16x16x32_bf16(wl.v, ahA[kk], accA[n], 0, 0, 0);
      accB[n] = __builtin_amdgcn_mfma_f32_16x16x32_bf16(wh.v, ahB[kk], accB[n], 0, 0, 0);
      accB[n] = __builtin_amdgcn_mfma_f32_16x16x32_bf16(wh.v, alB[kk], accB[n], 0, 0, 0);
      accB[n] = __builtin_amdgcn_mfma_f32_16x16x32_bf16(wl.v, ahB[kk], accB[n], 0, 0, 0);
    }
  }

  const float* bxA = bx + ((size_t)b*NV + svA)*NH;
  const float* cxA = cx + ((size_t)b*NV + dvA)*NH;
  const float* bxB = bx + ((size_t)b*NV + svB)*NH;
  const float* cxB = cx + ((size_t)b*NV + dvB)*NH;
  float* ehA = ehg + (size_t)eAc*NH;
  float* ehB = ehg + (size_t)eBc*NH;
  #pragma unroll
  for (int n=0;n<8;n++){
    int h0 = n*16 + lg*4;
    f32x4 ab4 = *(const f32x4*)(Ab + h0);
    f32x4 bA = *(const f32x4*)(bxA + h0);
    f32x4 cA = *(const f32x4*)(cxA + h0);
    f32x4 bB = *(const f32x4*)(bxB + h0);
    f32x4 cB = *(const f32x4*)(cxB + h0);
    f32x4 oA, oB;
    if (is_l0){
      f32x4 w4 = *(const f32x4*)(eWe + h0);
      f32x4 q4 = *(const f32x4*)(ebe + h0);
      #pragma unroll
      for (int j=0;j<4;j++){ oA[j] = evA*w4[j] + q4[j]; oB[j] = evB*w4[j] + q4[j]; }
    } else {
      oA = *(const f32x4*)(ehA + h0);
      oB = *(const f32x4*)(ehB + h0);
    }
    f32x4 nA, nB;
    #pragma unroll
    for (int j=0;j<4;j++){
      float vA = accA[n][j] + ab4[j] + bA[j] + cA[j];
      vA = vA > 0.f ? vA : 0.f;
      nA[j] = oA[j] + vA;
      float vB = accB[n][j] + ab4[j] + bB[j] + cB[j];
      vB = vB > 0.f ? vB : 0.f;
      nB[j] = oB[j] + vB;
    }
    if (eA < NE) *(f32x4*)(ehA + h0) = nA;
    if (eB < NE) *(f32x4*)(ehB + h0) = nB;
  }
}

// ---------------- fused layer-2 edge update + output MLP — round-9 proven form ------
// 512 threads, 128 KB LDS (all four matrices), one barrier.
__global__ __launch_bounds__(512) void k_edge_out(
    const float* __restrict__ eh, const short* __restrict__ Wt,
    const float* __restrict__ Ab, const float* __restrict__ bx,
    const float* __restrict__ cx, const int* __restrict__ ei,
    const float* __restrict__ b1, const float* __restrict__ W2,
    const float* __restrict__ b2, float* __restrict__ out)
{
  __shared__ short sW[4*NH*NH];         // 128 KB: p0=A2hi p1=A2lo p2=W1hi p3=W1lo
  {
    const short* A2hi = Wt + 2*NH*NH;
    const short* A2lo = Wt + 6*NH*NH;
    const short* W1hi = Wt + 3*NH*NH;
    const short* W1lo = Wt + 7*NH*NH;
    #pragma unroll
    for (int i=0;i<16;i++){
      int sidx = (threadIdx.x + i*512)*8;
      int p = i >> 2;
      int r = sidx & 16383;
      int hh = r >> 7, kw = r & 127;
      const short* src = (p==0)? A2hi : (p==1)? A2lo : (p==2)? W1hi : W1lo;
      s16x8 vv = *(const s16x8*)(src + r);
      *(s16x8*)(sW + p*16384 + hh*128 + (kw ^ ((hh&7)<<3))) = vv;
    }
  }
  __syncthreads();   // the ONLY barrier

  int blk  = blockIdx.x % EBLK;
  int b    = blockIdx.x / EBLK;
  int wave = threadIdx.x >> 6;
  int lane = threadIdx.x & 63;
  int l15 = lane & 15, lg = lane >> 4;
  int eA = blk*256 + wave*32 + l15;
  int eB = eA + 16;
  int eAc = eA < NE ? eA : NE-1;
  int eBc = eB < NE ? eB : NE-1;
  const float* ehg = eh + (size_t)b*NE*NH;
  const int* srcp = ei + b*2*NE;
  int svA = srcp[eAc], dvA = srcp[NE+eAc];
  int svB = srcp[eBc], dvB = srcp[NE+eBc];

  const float* pA = ehg + (size_t)eAc*NH + lg*8;
  const float* pB = ehg + (size_t)eBc*NH + lg*8;
  f32x4 rA[8], rB[8];
  #pragma unroll
  for (int kk=0;kk<4;kk++){
    rA[2*kk]   = *(const f32x4*)(pA + kk*32);
    rA[2*kk+1] = *(const f32x4*)(pA + kk*32 + 4);
  }
  #pragma unroll
  for (int kk=0;kk<4;kk++){
    rB[2*kk]   = *(const f32x4*)(pB + kk*32);
    rB[2*kk+1] = *(const f32x4*)(pB + kk*32 + 4);
  }

  bf16x8 ahA[4], alA[4], ahB[4], alB[4];
  #pragma unroll
  for (int kk=0;kk<4;kk++){
    union{ short s[8]; bf16x8 v; } uh, ul;
    #pragma unroll
    for (int j=0;j<4;j++){
      splitb(rA[2*kk][j],   uh.s[j],   ul.s[j]);
      splitb(rA[2*kk+1][j], uh.s[4+j], ul.s[4+j]);
    }
    ahA[kk] = uh.v; alA[kk] = ul.v;
  }
  #pragma unroll
  for (int kk=0;kk<4;kk++){
    union{ short s[8]; bf16x8 v; } uh, ul;
    #pragma unroll
    for (int j=0;j<4;j++){
      splitb(rB[2*kk][j],   uh.s[j],   ul.s[j]);
      splitb(rB[2*kk+1][j], uh.s[4+j], ul.s[4+j]);
    }
    ahB[kk] = uh.v; alB[kk] = ul.v;
  }

  f32x4 accA[8], accB[8];
  #pragma unroll
  for (int n=0;n<8;n++){ accA[n] = (f32x4){0.f,0.f,0.f,0.f}; accB[n] = (f32x4){0.f,0.f,0.f,0.f}; }
  #pragma unroll
  for (int kk=0;kk<4;kk++){
    #pragma unroll
    for (int n=0;n<8;n++){
      int row = n*16 + l15;
      int cofs = (kk*32 + lg*8) ^ ((l15&7)<<3);
      union{ s16x8 s; bf16x8 v; } wh, wl;
      wh.s = *(const s16x8*)(sW + row*128 + cofs);
      wl.s = *(const s16x8*)(sW + 16384 + row*128 + cofs);
      accA[n] = __builtin_amdgcn_mfma_f32_16x16x32_bf16(wh.v, ahA[kk], accA[n], 0, 0, 0);
      accA[n] = __builtin_amdgcn_mfma_f32_16x16x32_bf16(wh.v, alA[kk], accA[n], 0, 0, 0);
      accA[n] = __builtin_amdgcn_mfma_f32_16x16x32_bf16(wl.v, ahA[kk], accA[n], 0, 0, 0);
      accB[n] = __builtin_amdgcn_mfma_f32_16x16x32_bf16(wh.v, ahB[kk], accB[n], 0, 0, 0);
      accB[n] = __builtin_amdgcn_mfma_f32_16x16x32_bf16(wh.v, alB[kk], accB[n], 0, 0, 0);
      accB[n] = __builtin_amdgcn_mfma_f32_16x16x32_bf16(wl.v, ahB[kk], accB[n], 0, 0, 0);
    }
  }

  // epilogue: compute eh3 per (kk, half) and convert DIRECTLY to split-bf16
  // B-fragments (k-slot (kk,lg,j): h = 32kk+16(j>>2)+4lg+(j&3)); no f32 array.
  const float* bxA = bx + ((size_t)b*NV + svA)*NH;
  const float* cxA = cx + ((size_t)b*NV + dvA)*NH;
  const float* bxB = bx + ((size_t)b*NV + svB)*NH;
  const float* cxB = cx + ((size_t)b*NV + dvB)*NH;
  const float* ehA = ehg + (size_t)eAc*NH;
  const float* ehB = ehg + (size_t)eBc*NH;
  bf16x8 qhA[4], qlA[4], qhB[4], qlB[4];
  #pragma unroll
  for (int kk=0;kk<4;kk++){
    union{ short s[8]; bf16x8 v; } uhA, ulA, uhB, ulB;
    #pragma unroll
    for (int half=0; half<2; half++){
      int n = 2*kk + half;
      int h0 = n*16 + lg*4;
      f32x4 ab4 = *(const f32x4*)(Ab + h0);
      f32x4 bA4 = *(const f32x4*)(bxA + h0);
      f32x4 cA4 = *(const f32x4*)(cxA + h0);
      f32x4 oA4 = *(const f32x4*)(ehA + h0);
      f32x4 bB4 = *(const f32x4*)(bxB + h0);
      f32x4 cB4 = *(const f32x4*)(cxB + h0);
      f32x4 oB4 = *(const f32x4*)(ehB + h0);
      #pragma unroll
      for (int j=0;j<4;j++){
        float vA = accA[n][j] + ab4[j] + bA4[j] + cA4[j];
        vA = vA > 0.f ? vA : 0.f;
        float e3A = oA4[j] + vA;
        splitb(e3A, uhA.s[half*4+j], ulA.s[half*4+j]);
        float vB = accB[n][j] + ab4[j] + bB4[j] + cB4[j];
        vB = vB > 0.f ? vB : 0.f;
        float e3B = oB4[j] + vB;
        splitb(e3B, uhB.s[half*4+j], ulB.s[half*4+j]);
      }
    }
    qhA[kk] = uhA.v; qlA[kk] = ulA.v;
    qhB[kk] = uhB.v; qlB[kk] = ulB.v;
  }

  // Phase 2: W1 matmul, all operands LDS-resident (p2=hi, p3=lo)
  f32x4 acc2A[8], acc2B[8];
  #pragma unroll
  for (int n=0;n<8;n++){ acc2A[n] = (f32x4){0.f,0.f,0.f,0.f}; acc2B[n] = (f32x4){0.f,0.f,0.f,0.f}; }
  #pragma unroll
  for (int kk=0;kk<4;kk++){
    #pragma unroll
    for (int n=0;n<8;n++){
      int row = n*16 + l15;
      int cofs = (kk*32 + lg*8) ^ ((l15&7)<<3);
      union{ s16x8 s; bf16x8 v; } wh, wl;
      wh.s = *(const s16x8*)(sW + 2*16384 + row*128 + cofs);
      wl.s = *(const s16x8*)(sW + 3*16384 + row*128 + cofs);
      acc2A[n] = __builtin_amdgcn_mfma_f32_16x16x32_bf16(wh.v, qhA[kk], acc2A[n], 0, 0, 0);
      acc2A[n] = __builtin_amdgcn_mfma_f32_16x16x32_bf16(wh.v, qlA[kk], acc2A[n], 0, 0, 0);
      acc2A[n] = __builtin_amdgcn_mfma_f32_16x16x32_bf16(wl.v, qhA[kk], acc2A[n], 0, 0, 0);
      acc2B[n] = __builtin_amdgcn_mfma_f32_16x16x32_bf16(wh.v, qhB[kk], acc2B[n], 0, 0, 0);
      acc2B[n] = __builtin_amdgcn_mfma_f32_16x16x32_bf16(wh.v, qlB[kk], acc2B[n], 0, 0, 0);
      acc2B[n] = __builtin_amdgcn_mfma_f32_16x16x32_bf16(wl.v, qhB[kk], acc2B[n], 0, 0, 0);
    }
  }

  // W2 reduction + sigmoid
  float p0A = 0.f, p1A = 0.f, p0B = 0.f, p1B = 0.f;
  #pragma unroll
  for (int n=0;n<8;n++){
    int h0 = n*16 + lg*4;
    f32x4 b14 = *(const f32x4*)(b1 + h0);
    f32x4 wA  = *(const f32x4*)(W2 + h0*2);
    f32x4 wB  = *(const f32x4*)(W2 + h0*2 + 4);
    #pragma unroll
    for (int j=0;j<4;j++){
      float w20 = (j<2) ? wA[2*j]   : wB[2*(j-2)];
      float w21 = (j<2) ? wA[2*j+1] : wB[2*(j-2)+1];
      float hA = acc2A[n][j] + b14[j]; hA = hA > 0.f ? hA : 0.f;
      float hB = acc2B[n][j] + b14[j]; hB = hB > 0.f ? hB : 0.f;
      p0A += hA*w20; p1A += hA*w21;
      p0B += hB*w20; p1B += hB*w21;
    }
  }
  p0A += __shfl_xor(p0A, 16, 64); p0A += __shfl_xor(p0A, 32, 64);
  p1A += __shfl_xor(p1A, 16, 64); p1A += __shfl_xor(p1A, 32, 64);
  p0B += __shfl_xor(p0B, 16, 64); p0B += __shfl_xor(p0B, 32, 64);
  p1B += __shfl_xor(p1B, 16, 64); p1B += __shfl_xor(p1B, 32, 64);
  if (lg == 0){
    float bb0 = b2[0], bb1 = b2[1];
    if (eA < NE){
      float2 r; r.x = sigmoidf_(p0A + bb0); r.y = sigmoidf_(p1A + bb1);
      *(float2*)(out + ((size_t)b*NE + eA)*2) = r;
    }
    if (eB < NE){
      float2 r; r.x = sigmoidf_(p0B + bb0); r.y = sigmoidf_(p1B + bb1);
      *(float2*)(out + ((size_t)b*NE + eB)*2) = r;
    }
  }
}

extern "C" void kernel_launch(void* const* d_in, const int* in_sizes, int n_in,
                              void* d_out, int out_size, void* d_ws, size_t ws_size,
                              hipStream_t stream)
{
  const float* x   = (const float*)d_in[0];
  const float* e   = (const float*)d_in[1];
  const int*   ei  = (const int*)d_in[2];
  const float* nW  = (const float*)d_in[3];
  const float* nb  = (const float*)d_in[4];
  const float* eW  = (const float*)d_in[5];
  const float* eb  = (const float*)d_in[6];
  const float* UW  = (const float*)d_in[7];
  const float* Ub  = (const float*)d_in[8];
  const float* VW  = (const float*)d_in[9];
  const float* Vb  = (const float*)d_in[10];
  const float* AW  = (const float*)d_in[11];
  const float* Ab  = (const float*)d_in[12];
  const float* BW  = (const float*)d_in[13];
  const float* Bb  = (const float*)d_in[14];
  const float* CW  = (const float*)d_in[15];
  const float* Cb  = (const float*)d_in[16];
  const float* oW1 = (const float*)d_in[17];
  const float* ob1 = (const float*)d_in[18];
  const float* oW2 = (const float*)d_in[19];
  const float* ob2 = (const float*)d_in[20];
  float* out = (float*)d_out;

  char* ws = (char*)d_ws;
  size_t off = 0;
  auto alloc = [&](size_t bytes)->char*{
    char* p = ws + off;
    off += (bytes + 255) & ~(size_t)255;
    return p;
  };
  float* eh     = (float*)alloc((size_t)NB*NE*NH*4);
  float* xh     = (float*)alloc((size_t)NB*NV*NH*4);
  float* vx     = (float*)alloc((size_t)NB*NV*NH*4);
  float* bx     = (float*)alloc((size_t)NB*NV*NH*4);
  float* cx     = (float*)alloc((size_t)NB*NV*NH*4);
  float* ux     = (float*)alloc((size_t)NB*NV*NH*4);
  float* agg    = (float*)alloc((size_t)4*NB*NV*NH*4);
  short* Wt     = (short*)alloc((size_t)8*NH*NH*2);
  int* counts   = (int*)alloc((size_t)NB*NV*4);
  int* cursor   = (int*)alloc((size_t)NB*NV*4);
  int* offs     = (int*)alloc((size_t)NB*(NV+1)*4);
  int* csr      = (int*)alloc((size_t)NB*NE*4);
  (void)ws_size; (void)in_sizes; (void)n_in; (void)out_size;

  k_embed_nodes<<<(NB*NV*NH+255)/256, 256, 0, stream>>>(x, nW, nb, xh);
  k_trans_w<<<4, 256, 0, stream>>>(AW, oW1, Wt);
  k_zero<<<(NB*NV+255)/256, 256, 0, stream>>>(counts, NB*NV);
  k_count<<<(NB*NE+255)/256, 256, 0, stream>>>(ei, counts);
  k_scan<<<NB, 64, 0, stream>>>(counts, offs, cursor);
  k_scatter<<<(NB*NE+255)/256, 256, 0, stream>>>(ei, cursor, csr);

  for (int l=0; l<NL; l++){
    k_node_mm<<<NB*NV, 256, 0, stream>>>(xh, agg,
        VW + l*NH*NH, Vb + l*NH, BW + l*NH*NH, Bb + l*NH,
        CW + l*NH*NH, Cb + l*NH, UW + l*NH*NH, Ub + l*NH,
        vx, bx, cx, ux, l > 0 ? 1 : 0);
    if (l < NL-1)   // layer-2 agg only feeds dead xh_3
      k_agg<<<NB*NV*4, 128, 0, stream>>>(eh, e, eW, eb, vx, ei, csr, offs, agg, l==0 ? 1 : 0);
    if (l < NL-1)
      k_edge_update<<<NB*EBLK, 512, 0, stream>>>(eh, Wt + l*NH*NH, Ab + l*NH, bx, cx, ei,
                                                 e, eW, eb, l==0 ? 1 : 0);
    else
      k_edge_out<<<NB*EBLK, 512, 0, stream>>>(eh, Wt, Ab + l*NH, bx, cx, ei,
                                              ob1, oW2, ob2, out);
  }
}